// Round 5
// baseline (181.518 us; speedup 1.0000x reference)
//
#include <hip/hip_runtime.h>
#include <hip/hip_bf16.h>

#define B_SZ 4096
#define L_SZ 200

typedef __bf16 bf16x8 __attribute__((ext_vector_type(8)));
typedef float  f32x4  __attribute__((ext_vector_type(4)));

static __device__ inline unsigned short bfbits(float f) {
    return __builtin_bit_cast(unsigned short, (__bf16)f);
}
static __device__ inline float bf2f(unsigned short u) {
    return __builtin_bit_cast(float, (unsigned int)u << 16);
}

// ---------------------------------------------------------------------------
// L0 fused pre-pass, partitioned by blockIdx (all parts independent):
//   [0, 6250)          item_W fp32 -> item_bf bf16   (1.6e6 float4)
//   [6250, 6313)       cate_W fp32 -> cate_bf bf16   (16000 float4)
//   [6313, 6361)       W1/W2 -> MFMA B-fragment order (191 chunks, 4/block)
//   [6361]             zero BN acc + first_bad block-reduction
// ---------------------------------------------------------------------------
#define NB_ICVT 6250
#define NB_CCVT 63
#define NB_WFR  48

__global__ __launch_bounds__(256) void k_pre(
    const float* __restrict__ item_W, const float* __restrict__ cate_W,
    const float* __restrict__ W1, const float* __restrict__ W2,
    const int* __restrict__ history,
    ushort* __restrict__ item_bf, ushort* __restrict__ cate_bf,
    ushort* __restrict__ W1f, ushort* __restrict__ W2f,
    int* __restrict__ first_bad, float* __restrict__ acc)
{
    const int bid = blockIdx.x, tid = threadIdx.x;
    if (bid < NB_ICVT) {                                   // item table cvt
        int idx = bid * 256 + tid;
        float4 v = ((const float4*)item_W)[idx];
        ((ushort4*)item_bf)[idx] =
            make_ushort4(bfbits(v.x), bfbits(v.y), bfbits(v.z), bfbits(v.w));
    } else if (bid < NB_ICVT + NB_CCVT) {                  // cate table cvt
        int idx = (bid - NB_ICVT) * 256 + tid;
        if (idx < 16000) {
            float4 v = ((const float4*)cate_W)[idx];
            ((ushort4*)cate_bf)[idx] =
                make_ushort4(bfbits(v.x), bfbits(v.y), bfbits(v.z), bfbits(v.w));
        }
    } else if (bid < NB_ICVT + NB_CCVT + NB_WFR) {         // W fragment swizzle
        const int chunk = (bid - NB_ICVT - NB_CCVT) * 4 + (tid >> 6);
        const int lane = tid & 63, nr = lane & 15, quad = lane >> 4;
        if (chunk < 191) {
            ushort v[8];
            if (chunk < 156) {                             // W1: 13 oT x 12 kS
                const int oT = chunk / 12, kS = chunk % 12;
                const int o = oT * 16 + nr;
                #pragma unroll
                for (int j = 0; j < 8; ++j) {
                    int k = kS * 32 + quad * 8 + j;
                    v[j] = (o < 200) ? bfbits(W1[(size_t)o * 384 + k]) : (ushort)0;
                }
                ushort* dst = W1f + ((size_t)chunk * 64 + lane) * 8;
                *(ushort4*)(dst)     = make_ushort4(v[0], v[1], v[2], v[3]);
                *(ushort4*)(dst + 4) = make_ushort4(v[4], v[5], v[6], v[7]);
            } else {                                       // W2: 5 oT x 7 kS
                const int idx = chunk - 156;
                const int oT = idx / 7, kS = idx % 7;
                const int o = oT * 16 + nr;
                #pragma unroll
                for (int j = 0; j < 8; ++j) {
                    int k = kS * 32 + quad * 8 + j;
                    v[j] = (k < 200) ? bfbits(W2[(size_t)o * 200 + k]) : (ushort)0;
                }
                ushort* dst = W2f + ((size_t)idx * 64 + lane) * 8;
                *(ushort4*)(dst)     = make_ushort4(v[0], v[1], v[2], v[3]);
                *(ushort4*)(dst + 4) = make_ushort4(v[4], v[5], v[6], v[7]);
            }
        }
    } else {                                               // prep
        acc[tid] = 0.f; acc[256 + tid] = 0.f; acc[512 + tid] = 0.f;
        int m = B_SZ;
        for (int b = tid; b < B_SZ; b += 256)
            if (history[(size_t)b * L_SZ] == 0) m = min(m, b);
        __shared__ int red[256];
        red[tid] = m;
        __syncthreads();
        for (int s = 128; s > 0; s >>= 1) {
            if (tid < s) red[tid] = min(red[tid], red[tid + s]);
            __syncthreads();
        }
        if (tid == 0) first_bad[0] = red[0];
    }
}

// ---------------------------------------------------------------------------
// K1: per-row masked mean-pool from bf16 tables + build xb[b,384] (bf16).
// 16 subgroups of 16 lanes; subgroup p handles positions l = p, p+16, ...
// Within a subgroup: lanes 0..7 item row (bf16x8 each), lanes 8..15 cate row.
// NOTE: no first_bad here — row-halt masking deferred to bnstats/l1.
// ---------------------------------------------------------------------------
__global__ __launch_bounds__(256) void k_pool(
    const int* __restrict__ user, const int* __restrict__ item,
    const int* __restrict__ history, const int* __restrict__ cate_list,
    const float* __restrict__ user_W, const float* __restrict__ item_W,
    const float* __restrict__ cate_W,
    const ushort* __restrict__ item_bf, const ushort* __restrict__ cate_bf,
    ushort* __restrict__ xb)
{
    const int b = blockIdx.x;
    const int tid = threadIdx.x;
    __shared__ int sh_item[L_SZ];
    __shared__ int sh_cid[L_SZ];
    __shared__ int s_fz;
    __shared__ __align__(16) float red[16][128];
    if (tid == 0) s_fz = L_SZ;
    __syncthreads();
    if (tid < L_SZ) {
        int h = history[(size_t)b * L_SZ + tid];
        sh_item[tid] = h;
        if (tid >= 1 && h == 0) atomicMin(&s_fz, tid);
        sh_cid[tid] = cate_list[h];
    }
    __syncthreads();
    const int valid = s_fz;
    const float inv_cnt = 1.0f / (float)max(valid, 1);

    const int p = tid >> 4, sub = (tid >> 3) & 1, q = tid & 7;
    const ushort* tab = sub ? cate_bf : item_bf;
    const int*    ids = sub ? sh_cid : sh_item;
    float a0 = 0.f, a1_ = 0.f, a2_ = 0.f, a3 = 0.f, a4 = 0.f, a5 = 0.f, a6 = 0.f, a7 = 0.f;
    int l = p;
    for (; l + 16 < valid; l += 32) {
        bf16x8 v0 = *(const bf16x8*)(tab + (size_t)ids[l] * 64 + q * 8);
        bf16x8 v1 = *(const bf16x8*)(tab + (size_t)ids[l + 16] * 64 + q * 8);
        a0 += (float)v0[0] + (float)v1[0]; a1_ += (float)v0[1] + (float)v1[1];
        a2_ += (float)v0[2] + (float)v1[2]; a3 += (float)v0[3] + (float)v1[3];
        a4 += (float)v0[4] + (float)v1[4]; a5 += (float)v0[5] + (float)v1[5];
        a6 += (float)v0[6] + (float)v1[6]; a7 += (float)v0[7] + (float)v1[7];
    }
    if (l < valid) {
        bf16x8 v0 = *(const bf16x8*)(tab + (size_t)ids[l] * 64 + q * 8);
        a0 += (float)v0[0]; a1_ += (float)v0[1]; a2_ += (float)v0[2]; a3 += (float)v0[3];
        a4 += (float)v0[4]; a5 += (float)v0[5]; a6 += (float)v0[6]; a7 += (float)v0[7];
    }
    float* rp = &red[p][sub * 64 + q * 8];
    *(float4*)(rp)     = make_float4(a0, a1_, a2_, a3);
    *(float4*)(rp + 4) = make_float4(a4, a5, a6, a7);
    __syncthreads();

    ushort* xrow = xb + (size_t)b * 384;
    if (tid < 128) {
        float s = 0.f;
        #pragma unroll
        for (int g = 0; g < 16; ++g) s += red[g][tid];
        xrow[256 + tid] = bfbits(s * inv_cnt);
        xrow[tid] = bfbits(user_W[(size_t)user[b] * 128 + tid]);
    } else if (tid < 192) {
        int f = tid - 128;
        xrow[128 + f] = bfbits(item_W[(size_t)item[b] * 64 + f]);
    } else {
        int f = tid - 192;
        xrow[192 + f] = bfbits(cate_W[(size_t)cate_list[item[b]] * 64 + f]);
    }
}

// ---------------------------------------------------------------------------
// K2: BN batch stats; applies row-halt mask (pooled cols of rows >= first_bad
// read as 0, matching reference row_active semantics).
// ---------------------------------------------------------------------------
__global__ __launch_bounds__(384) void k_bnstats(const ushort* __restrict__ xb,
                                                 const int* __restrict__ first_bad,
                                                 float* __restrict__ acc) {
    const int f = threadIdx.x;
    const int r0 = blockIdx.x * 64;
    const int fb = first_bad[0];
    const bool pooled = (f >= 256);
    float s = 0.f, s2 = 0.f;
    for (int r = r0; r < r0 + 64; ++r) {
        float v = bf2f(xb[(size_t)r * 384 + f]);
        if (pooled && r >= fb) v = 0.f;
        s += v; s2 += v * v;
    }
    atomicAdd(&acc[f], s);
    atomicAdd(&acc[384 + f], s2);
}

// ---------------------------------------------------------------------------
// K3a: layer 1 — wave-autonomous MFMA tiles. wave wid -> (mT=wid/13, oT=wid%13).
// BN finalize inlined per block; BN affine applied in-register to A-fragments;
// row-halt mask zeroes pooled cols (kS>=8) for rows >= first_bad pre-affine.
// ---------------------------------------------------------------------------
__global__ __launch_bounds__(256) void k_l1(
    const ushort* __restrict__ xb, const float* __restrict__ accv,
    const float* __restrict__ gamma, const float* __restrict__ beta,
    const ushort* __restrict__ W1f, const float* __restrict__ b1,
    const float* __restrict__ a1p, const int* __restrict__ first_bad,
    ushort* __restrict__ h1b)
{
    __shared__ float As[384], Cs[384];
    const int tid = threadIdx.x;
    for (int f = tid; f < 384; f += 256) {
        const float inv_b = 1.0f / (float)B_SZ;
        float mean = accv[f] * inv_b;
        float var  = accv[384 + f] * inv_b - mean * mean;
        float a = gamma[f] * rsqrtf(var + 1e-5f);
        As[f] = a;
        Cs[f] = beta[f] - mean * a;
    }
    __syncthreads();

    const int lane = tid & 63, wv = tid >> 6;
    const int nr = lane & 15, quad = lane >> 4;
    const int wid = blockIdx.x * 4 + wv;
    const int mT = wid / 13, oT = wid - mT * 13;
    const int o = oT * 16 + nr;
    const float a1 = a1p[0];
    const int fb = first_bad[0];
    const bool badrow = (mT * 16 + nr) >= fb;

    float bias = (o < 200) ? b1[o] : 0.f;
    f32x4 acc = {bias, bias, bias, bias};
    const ushort* xrow = xb + (size_t)(mT * 16 + nr) * 384;

    #pragma unroll 2
    for (int kS = 0; kS < 8; ++kS) {                       // user/item cols
        const int kc = kS * 32 + quad * 8;
        bf16x8 a8 = *(const bf16x8*)(xrow + kc);
        float4 A0 = *(const float4*)&As[kc], A1 = *(const float4*)&As[kc + 4];
        float4 C0 = *(const float4*)&Cs[kc], C1 = *(const float4*)&Cs[kc + 4];
        bf16x8 w;
        w[0] = (__bf16)((float)a8[0] * A0.x + C0.x);
        w[1] = (__bf16)((float)a8[1] * A0.y + C0.y);
        w[2] = (__bf16)((float)a8[2] * A0.z + C0.z);
        w[3] = (__bf16)((float)a8[3] * A0.w + C0.w);
        w[4] = (__bf16)((float)a8[4] * A1.x + C1.x);
        w[5] = (__bf16)((float)a8[5] * A1.y + C1.y);
        w[6] = (__bf16)((float)a8[6] * A1.z + C1.z);
        w[7] = (__bf16)((float)a8[7] * A1.w + C1.w);
        bf16x8 bfr = *(const bf16x8*)(W1f + (((size_t)oT * 12 + kS) * 64 + lane) * 8);
        acc = __builtin_amdgcn_mfma_f32_16x16x32_bf16(w, bfr, acc, 0, 0, 0);
    }
    #pragma unroll 2
    for (int kS = 8; kS < 12; ++kS) {                      // pooled cols: mask
        const int kc = kS * 32 + quad * 8;
        bf16x8 a8 = *(const bf16x8*)(xrow + kc);
        if (badrow) {
            #pragma unroll
            for (int j = 0; j < 8; ++j) a8[j] = (__bf16)0.f;
        }
        float4 A0 = *(const float4*)&As[kc], A1 = *(const float4*)&As[kc + 4];
        float4 C0 = *(const float4*)&Cs[kc], C1 = *(const float4*)&Cs[kc + 4];
        bf16x8 w;
        w[0] = (__bf16)((float)a8[0] * A0.x + C0.x);
        w[1] = (__bf16)((float)a8[1] * A0.y + C0.y);
        w[2] = (__bf16)((float)a8[2] * A0.z + C0.z);
        w[3] = (__bf16)((float)a8[3] * A0.w + C0.w);
        w[4] = (__bf16)((float)a8[4] * A1.x + C1.x);
        w[5] = (__bf16)((float)a8[5] * A1.y + C1.y);
        w[6] = (__bf16)((float)a8[6] * A1.z + C1.z);
        w[7] = (__bf16)((float)a8[7] * A1.w + C1.w);
        bf16x8 bfr = *(const bf16x8*)(W1f + (((size_t)oT * 12 + kS) * 64 + lane) * 8);
        acc = __builtin_amdgcn_mfma_f32_16x16x32_bf16(w, bfr, acc, 0, 0, 0);
    }

    #pragma unroll
    for (int r = 0; r < 4; ++r) {
        int row = mT * 16 + quad * 4 + r;
        float s = acc[r];
        s = (s >= 0.f) ? s : a1 * s;
        h1b[(size_t)row * 224 + o] = bfbits(s);
        if (oT == 12) h1b[(size_t)row * 224 + o + 16] = 0;  // zero pad cols 208..223
    }
}

// ---------------------------------------------------------------------------
// K3b: layers 2+3 — one wave per 16-row tile, no LDS, no barriers.
// ---------------------------------------------------------------------------
__global__ __launch_bounds__(256) void k_l23(
    const ushort* __restrict__ h1b, const ushort* __restrict__ W2f,
    const float* __restrict__ b2, const float* __restrict__ a2p,
    const float* __restrict__ W3, const float* __restrict__ b3,
    float* __restrict__ out)
{
    const int tid = threadIdx.x;
    const int lane = tid & 63, wv = tid >> 6;
    const int nr = lane & 15, quad = lane >> 4;
    const int mT = blockIdx.x * 4 + wv;
    const float a2 = a2p[0];

    f32x4 acc[5];
    #pragma unroll
    for (int i = 0; i < 5; ++i) {
        float bb = b2[i * 16 + nr];
        acc[i] = (f32x4){bb, bb, bb, bb};
    }
    const ushort* hrow = h1b + (size_t)(mT * 16 + nr) * 224;
    for (int kS = 0; kS < 7; ++kS) {
        bf16x8 a8 = *(const bf16x8*)(hrow + kS * 32 + quad * 8);
        #pragma unroll
        for (int i = 0; i < 5; ++i) {
            bf16x8 bfr = *(const bf16x8*)(W2f + (((size_t)i * 7 + kS) * 64 + lane) * 8);
            acc[i] = __builtin_amdgcn_mfma_f32_16x16x32_bf16(a8, bfr, acc[i], 0, 0, 0);
        }
    }

    float w0[5], w1[5];
    #pragma unroll
    for (int i = 0; i < 5; ++i) {
        w0[i] = W3[i * 16 + nr];
        w1[i] = W3[80 + i * 16 + nr];
    }
    f32x4 p0 = {0.f, 0.f, 0.f, 0.f}, p1 = {0.f, 0.f, 0.f, 0.f};
    #pragma unroll
    for (int i = 0; i < 5; ++i) {
        #pragma unroll
        for (int r = 0; r < 4; ++r) {
            float s = acc[i][r];
            s = (s >= 0.f) ? s : a2 * s;
            p0[r] += s * w0[i];
            p1[r] += s * w1[i];
        }
    }
    #pragma unroll
    for (int m = 1; m < 16; m <<= 1) {
        #pragma unroll
        for (int r = 0; r < 4; ++r) {
            p0[r] += __shfl_xor(p0[r], m, 64);
            p1[r] += __shfl_xor(p1[r], m, 64);
        }
    }
    if (nr == 0) {
        float B0 = b3[0], B1 = b3[1];
        #pragma unroll
        for (int r = 0; r < 4; ++r) {
            float l0 = p0[r] + B0, l1 = p1[r] + B1;
            float mx = fmaxf(l0, l1);
            float e0 = expf(l0 - mx), e1 = expf(l1 - mx);
            float inv = 1.0f / (e0 + e1);
            int row = mT * 16 + quad * 4 + r;
            *(float2*)(out + (size_t)row * 2) = make_float2(e0 * inv, e1 * inv);
        }
    }
}

// ---------------------------------------------------------------------------
extern "C" void kernel_launch(void* const* d_in, const int* in_sizes, int n_in,
                              void* d_out, int out_size, void* d_ws, size_t ws_size,
                              hipStream_t stream) {
    const int*   user      = (const int*)  d_in[0];
    const int*   item      = (const int*)  d_in[1];
    const int*   history   = (const int*)  d_in[2];
    const int*   cate_list = (const int*)  d_in[4];
    const float* user_W    = (const float*)d_in[5];
    const float* item_W    = (const float*)d_in[6];
    const float* cate_W    = (const float*)d_in[7];
    const float* gamma     = (const float*)d_in[8];
    const float* beta      = (const float*)d_in[9];
    const float* W1        = (const float*)d_in[10];
    const float* b1        = (const float*)d_in[11];
    const float* a1        = (const float*)d_in[12];
    const float* W2        = (const float*)d_in[13];
    const float* b2        = (const float*)d_in[14];
    const float* a2        = (const float*)d_in[15];
    const float* W3        = (const float*)d_in[16];
    const float* b3        = (const float*)d_in[17];
    float* out = (float*)d_out;

    // ws byte layout (64B-aligned):
    //        0 first_bad (int)
    //       64 acc[768] fp32
    //     3200 xb  [4096*384] bf16     (3,145,728)
    //  3148928 h1b [4096*224] bf16     (1,835,008)
    //  4983936 W1f [156*64*8] bf16     (159,744)
    //  5143680 W2f [35*64*8]  bf16     (35,840)
    //  5179520 item_bf [100000*64]     (12,800,000)
    // 17979520 cate_bf [1000*64]       (128,000)
    char* ws = (char*)d_ws;
    int*    first_bad = (int*)   ws;
    float*  acc       = (float*)(ws + 64);
    ushort* xb        = (ushort*)(ws + 3200);
    ushort* h1b       = (ushort*)(ws + 3148928);
    ushort* W1f       = (ushort*)(ws + 4983936);
    ushort* W2f       = (ushort*)(ws + 5143680);
    ushort* item_bf   = (ushort*)(ws + 5179520);
    ushort* cate_bf   = (ushort*)(ws + 17979520);

    hipLaunchKernelGGL(k_pre,     dim3(NB_ICVT + NB_CCVT + NB_WFR + 1), dim3(256), 0, stream,
                       item_W, cate_W, W1, W2, history,
                       item_bf, cate_bf, W1f, W2f, first_bad, acc);
    hipLaunchKernelGGL(k_pool,    dim3(B_SZ), dim3(256), 0, stream,
                       user, item, history, cate_list, user_W, item_W, cate_W,
                       item_bf, cate_bf, xb);
    hipLaunchKernelGGL(k_bnstats, dim3(64),   dim3(384), 0, stream, xb, first_bad, acc);
    hipLaunchKernelGGL(k_l1,      dim3(832),  dim3(256), 0, stream,
                       xb, acc, gamma, beta, W1f, b1, a1, first_bad, h1b);
    hipLaunchKernelGGL(k_l23,     dim3(64),   dim3(256), 0, stream,
                       h1b, W2f, b2, a2, W3, b3, out);
}